// Round 9
// baseline (382.526 us; speedup 1.0000x reference)
//
#include <hip/hip_runtime.h>
#include <hip/hip_bf16.h>
#include <stdint.h>

#define B_  4
#define T_  2048
#define DM  1024
#define H_  4
#define DK_ 128
#define DV_ 256
#define KD  512     // H_*DK_
#define VD  1024    // H_*DV_
#define NCH 32      // num chunks
#define CC  64      // chunk len
#define BT  8192    // B_*T_
#define SCALE 0.08838834764831845f   // 1/sqrt(128)
#define GNORM_INV 0.0625f            // 1/16

typedef __attribute__((ext_vector_type(8))) short short8;   // 8 bf16 (4 VGPRs)
typedef __attribute__((ext_vector_type(4))) float f32x4;
typedef uint32_t u32;
typedef unsigned short ushort_t;

__device__ inline ushort_t f2b(float f) {               // f32 -> bf16 RNE
    u32 u = __builtin_bit_cast(u32, f);
    u32 r = (u + 0x7fffu + ((u >> 16) & 1u)) >> 16;
    return (ushort_t)r;
}
__device__ inline float b2f(ushort_t h) {
    return __builtin_bit_cast(float, (u32)h << 16);
}
__device__ inline void unpack2(u32 u, float& lo, float& hi) {
    lo = __builtin_bit_cast(float, u << 16);
    hi = __builtin_bit_cast(float, u & 0xffff0000u);
}
// async global->LDS, 16B per lane; LDS dest is wave-uniform base + lane*16
__device__ inline void gload_lds16(const void* g, void* l) {
    __builtin_amdgcn_global_load_lds(
        (const __attribute__((address_space(1))) uint32_t*)g,
        (__attribute__((address_space(3))) uint32_t*)l, 16, 0, 0);
}

// ---------------------------------------------------------------------------
// cvtx: f32 -> bf16 (8 elems/thread)
// ---------------------------------------------------------------------------
__global__ __launch_bounds__(256)
void cvtx(const float* __restrict__ x, ushort_t* __restrict__ xb, int n) {
    int idx = (blockIdx.x * 256 + threadIdx.x) * 8;
    if (idx >= n) return;
    float4 a = *(const float4*)&x[idx];
    float4 b = *(const float4*)&x[idx + 4];
    uint4 p;
    p.x = (u32)f2b(a.x) | ((u32)f2b(a.y) << 16);
    p.y = (u32)f2b(a.z) | ((u32)f2b(a.w) << 16);
    p.z = (u32)f2b(b.x) | ((u32)f2b(b.y) << 16);
    p.w = (u32)f2b(b.z) | ((u32)f2b(b.w) << 16);
    *(uint4*)&xb[idx] = p;
}

// ---------------------------------------------------------------------------
// tcvt: W[K][N] f32 -> Wt[N][K] bf16 (transpose + convert), 32x32 LDS tiles
// ---------------------------------------------------------------------------
__global__ __launch_bounds__(256)
void tcvt(const float* __restrict__ W, ushort_t* __restrict__ Wt, int K, int N) {
    __shared__ float tile[32][33];
    const int k0 = blockIdx.x * 32, n0 = blockIdx.y * 32;
    const int r = threadIdx.x >> 3, c4 = (threadIdx.x & 7) * 4;
    float4 wv = *(const float4*)&W[(size_t)(k0 + r) * N + n0 + c4];
    tile[r][c4 + 0] = wv.x; tile[r][c4 + 1] = wv.y;
    tile[r][c4 + 2] = wv.z; tile[r][c4 + 3] = wv.w;
    __syncthreads();
    u32 lo = (u32)f2b(tile[c4 + 0][r]) | ((u32)f2b(tile[c4 + 1][r]) << 16);
    u32 hi = (u32)f2b(tile[c4 + 2][r]) | ((u32)f2b(tile[c4 + 3][r]) << 16);
    uint2 o2; o2.x = lo; o2.y = hi;
    *(uint2*)&Wt[(size_t)(n0 + r) * K + k0 + c4] = o2;
}

// ---------------------------------------------------------------------------
// w1trans: W1[1024][16] f32 -> w1t[16][1024] bf16
// ---------------------------------------------------------------------------
__global__ __launch_bounds__(256)
void w1trans(const float* __restrict__ W1, ushort_t* __restrict__ w1t) {
    int idx = blockIdx.x * 256 + threadIdx.x;   // 16384
    int k = idx >> 4, n = idx & 15;
    w1t[n * 1024 + k] = f2b(W1[k * 16 + n]);
}

// ---------------------------------------------------------------------------
// gemm_qkv: fused q/k/v projection, bf16 out into qkv[bt][2048].
// Grid 1024 = 64bx x 16by. 2D XCD partition: XCD (4x2), each owns 16bx x 8by
// so A is fetched by only 2 XCDs and B by 4 (cuts 133MB -> ~55MB HBM fetch).
// ---------------------------------------------------------------------------
__global__ __launch_bounds__(256)
void gemm_qkv(const ushort_t* __restrict__ A, const ushort_t* __restrict__ Bt,
              ushort_t* __restrict__ qkvo) {
    __shared__ ushort_t Al[128 * 32];
    __shared__ ushort_t Bl[128 * 32];
    const int wg = blockIdx.x;
    const int xcd = wg & 7, local = wg >> 3;      // 128 blocks per XCD
    const int bx = (xcd & 3) * 16 + (local & 15); // 0..63
    const int by = (xcd >> 2) * 8 + (local >> 4); // 0..15
    const int t = threadIdx.x;
    const int wave = t >> 6, lane = t & 63;
    const int wr = wave >> 1, wc = wave & 1;
    const int row0 = bx * 128, col0 = by * 128;
    const int lm = lane & 15, lk = (lane >> 4) * 8;

    const int b0 = t * 16;
    const int r0 = b0 >> 6, c0 = (b0 & 63) >> 1;
    const int r1 = (4096 + b0) >> 6, c1 = ((4096 + b0) & 63) >> 1;
    ushort_t* ldsA0 = &Al[(wave * 1024) >> 1];
    ushort_t* ldsA1 = &Al[(4096 + wave * 1024) >> 1];
    ushort_t* ldsB0 = &Bl[(wave * 1024) >> 1];
    ushort_t* ldsB1 = &Bl[(4096 + wave * 1024) >> 1];

    f32x4 acc[4][4];
    #pragma unroll
    for (int i = 0; i < 4; ++i)
        #pragma unroll
        for (int j = 0; j < 4; ++j) acc[i][j] = f32x4{0.f, 0.f, 0.f, 0.f};

    const ushort_t* Ap = A + (size_t)row0 * DM;
    const ushort_t* Bp = Bt + (size_t)col0 * DM;

    for (int k0 = 0; k0 < DM; k0 += 32) {
        __syncthreads();
        gload_lds16(Ap + (size_t)r0 * DM + k0 + c0, ldsA0);
        gload_lds16(Ap + (size_t)r1 * DM + k0 + c1, ldsA1);
        gload_lds16(Bp + (size_t)r0 * DM + k0 + c0, ldsB0);
        gload_lds16(Bp + (size_t)r1 * DM + k0 + c1, ldsB1);
        __syncthreads();
        short8 af[4], bfr[4];
        #pragma unroll
        for (int f = 0; f < 4; ++f)
            af[f] = *(const short8*)(&Al[(wr * 64 + f * 16 + lm) * 32 + lk]);
        #pragma unroll
        for (int f = 0; f < 4; ++f)
            bfr[f] = *(const short8*)(&Bl[(wc * 64 + f * 16 + lm) * 32 + lk]);
        #pragma unroll
        for (int i = 0; i < 4; ++i)
            #pragma unroll
            for (int j = 0; j < 4; ++j)
                acc[i][j] = __builtin_amdgcn_mfma_f32_16x16x32_bf16(af[i], bfr[j], acc[i][j], 0, 0, 0);
    }
    const int orow = row0 + wr * 64 + (lane >> 4) * 4;
    const int ocol = col0 + wc * 64 + lm;         // 0..2047
    #pragma unroll
    for (int i = 0; i < 4; ++i)
        #pragma unroll
        for (int j = 0; j < 4; ++j)
            #pragma unroll
            for (int e = 0; e < 4; ++e)
                qkvo[(size_t)(orow + i * 16 + e) * 2048 + ocol + j * 16] = f2b(acc[i][j][e]);
}

// ---------------------------------------------------------------------------
// gemm_bf16<OUTBF>: C[8192,1024] = A[8192,1024]bf16 @ Wt[1024,1024]^T.
// Grid 512 = 64bx x 8by. 2D XCD partition: XCD (4x2), each owns 16bx x 4by.
// ---------------------------------------------------------------------------
template<int OUTBF>
__global__ __launch_bounds__(256)
void gemm_bf16(const ushort_t* __restrict__ A, const ushort_t* __restrict__ Bt,
               void* __restrict__ Cout) {
    __shared__ ushort_t Al[128 * 32];
    __shared__ ushort_t Bl[128 * 32];
    const int wg = blockIdx.x;
    const int xcd = wg & 7, local = wg >> 3;      // 64 blocks per XCD
    const int bx = (xcd & 3) * 16 + (local & 15); // 0..63
    const int by = (xcd >> 2) * 4 + (local >> 4); // 0..7
    const int t = threadIdx.x;
    const int wave = t >> 6, lane = t & 63;
    const int wr = wave >> 1, wc = wave & 1;
    const int row0 = bx * 128, col0 = by * 128;
    const int lm = lane & 15, lk = (lane >> 4) * 8;

    const int b0 = t * 16;
    const int r0 = b0 >> 6, c0 = (b0 & 63) >> 1;
    const int r1 = (4096 + b0) >> 6, c1 = ((4096 + b0) & 63) >> 1;
    ushort_t* ldsA0 = &Al[(wave * 1024) >> 1];
    ushort_t* ldsA1 = &Al[(4096 + wave * 1024) >> 1];
    ushort_t* ldsB0 = &Bl[(wave * 1024) >> 1];
    ushort_t* ldsB1 = &Bl[(4096 + wave * 1024) >> 1];

    f32x4 acc[4][4];
    #pragma unroll
    for (int i = 0; i < 4; ++i)
        #pragma unroll
        for (int j = 0; j < 4; ++j) acc[i][j] = f32x4{0.f, 0.f, 0.f, 0.f};

    const ushort_t* Ap = A + (size_t)row0 * DM;
    const ushort_t* Bp = Bt + (size_t)col0 * DM;

    for (int k0 = 0; k0 < DM; k0 += 32) {
        __syncthreads();
        gload_lds16(Ap + (size_t)r0 * DM + k0 + c0, ldsA0);
        gload_lds16(Ap + (size_t)r1 * DM + k0 + c1, ldsA1);
        gload_lds16(Bp + (size_t)r0 * DM + k0 + c0, ldsB0);
        gload_lds16(Bp + (size_t)r1 * DM + k0 + c1, ldsB1);
        __syncthreads();
        short8 af[4], bfr[4];
        #pragma unroll
        for (int f = 0; f < 4; ++f)
            af[f] = *(const short8*)(&Al[(wr * 64 + f * 16 + lm) * 32 + lk]);
        #pragma unroll
        for (int f = 0; f < 4; ++f)
            bfr[f] = *(const short8*)(&Bl[(wc * 64 + f * 16 + lm) * 32 + lk]);
        #pragma unroll
        for (int i = 0; i < 4; ++i)
            #pragma unroll
            for (int j = 0; j < 4; ++j)
                acc[i][j] = __builtin_amdgcn_mfma_f32_16x16x32_bf16(af[i], bfr[j], acc[i][j], 0, 0, 0);
    }
    const int orow = row0 + wr * 64 + (lane >> 4) * 4;
    const int ocol = col0 + wc * 64 + lm;
    #pragma unroll
    for (int i = 0; i < 4; ++i)
        #pragma unroll
        for (int j = 0; j < 4; ++j)
            #pragma unroll
            for (int e = 0; e < 4; ++e) {
                int rr = orow + i * 16 + e, cc = ocol + j * 16;
                if (OUTBF) ((ushort_t*)Cout)[(size_t)rr * 1024 + cc] = f2b(acc[i][j][e]);
                else       ((float*)Cout)[(size_t)rr * 1024 + cc]   = acc[i][j][e];
            }
}

// ---------------------------------------------------------------------------
// lowrank (MFMA): tmp[8192][16] = xbf @ w1t^T.  128 blocks, 64 rows each.
// ---------------------------------------------------------------------------
__global__ __launch_bounds__(256)
void lowrank_mfma(const ushort_t* __restrict__ xbf, const ushort_t* __restrict__ w1t,
                  float* __restrict__ tmp) {
    const int t = threadIdx.x;
    const int w = t >> 6, lane = t & 63;
    const int lm = lane & 15, lg = lane >> 4;
    const int row0 = blockIdx.x * 64 + w * 16;
    f32x4 acc = {0.f, 0.f, 0.f, 0.f};
    #pragma unroll
    for (int kk = 0; kk < 32; ++kk) {
        short8 a = *(const short8*)&xbf[(size_t)(row0 + lm) * DM + kk * 32 + lg * 8];
        short8 b = *(const short8*)&w1t[(size_t)lm * DM + kk * 32 + lg * 8];
        acc = __builtin_amdgcn_mfma_f32_16x16x32_bf16(a, b, acc, 0, 0, 0);
    }
    #pragma unroll
    for (int e = 0; e < 4; ++e)
        tmp[(size_t)(row0 + lg * 4 + e) * 16 + lm] = acc[e];
}

// ---------------------------------------------------------------------------
// gateprep (fused gatek): per block (bh,c), 128 thr (one per dk channel d).
// gk_i = log_sigmoid(tmp16[i]·W2[:,cg] + b[cg])/16 computed on the fly
// (two passes: total, then cumulative). q,k read bf16 from qkv.
// ---------------------------------------------------------------------------
__global__ __launch_bounds__(128)
void gateprep_kernel(const ushort_t* __restrict__ qkv, const float* __restrict__ tmp16,
                     const float* __restrict__ W2, const float* __restrict__ bias,
                     ushort_t* __restrict__ qgb, ushort_t* __restrict__ kib,
                     ushort_t* __restrict__ kgb, float* __restrict__ glast) {
    __shared__ float sm[64][16];
    const int bid = blockIdx.x;
    const int c = bid & 31, bh = bid >> 5;
    const int b = bh >> 2, h = bh & 3;
    const int d = threadIdx.x;
    const int t0 = b * T_ + c * CC;
    const int cg = h * DK_ + d;               // gate/q column 0..511
    const int obase = bid * (CC * DK_) + d;

    // stage tmp16 rows [t0, t0+64) into LDS (1024 f32)
    #pragma unroll
    for (int m = 0; m < 2; ++m) {
        int idx = d + m * 128;                // 256 float4
        int row = idx >> 2, col4 = (idx & 3) * 4;
        *(float4*)&sm[row][col4] = *(const float4*)&tmp16[(size_t)(t0 + row) * 16 + col4];
    }
    __syncthreads();

    float w2c[16];
    #pragma unroll
    for (int j = 0; j < 16; ++j) w2c[j] = W2[j * KD + cg];
    const float bs = bias[cg];

    // pass 1: total decay
    float total = 0.f;
    for (int i = 0; i < CC; ++i) {
        float z = bs;
        #pragma unroll
        for (int j = 0; j < 16; ++j) z += sm[i][j] * w2c[j];
        total += (fminf(z, 0.f) - log1pf(expf(-fabsf(z)))) * GNORM_INV;
    }

    // pass 2: cumulative + outputs
    float G = 0.f;
    for (int i = 0; i < CC; ++i) {
        float z = bs;
        #pragma unroll
        for (int j = 0; j < 16; ++j) z += sm[i][j] * w2c[j];
        G += (fminf(z, 0.f) - log1pf(expf(-fabsf(z)))) * GNORM_INV;
        const size_t qrow = (size_t)(t0 + i) * 2048;
        float qv = b2f(qkv[qrow + cg]);
        float kv = b2f(qkv[qrow + 512 + cg]);
        qgb[obase + i * DK_] = f2b(qv * expf(G) * SCALE);
        kib[obase + i * DK_] = f2b(kv * expf(-G));
        kgb[obase + i * DK_] = f2b(kv * expf(total - G));
    }
    glast[bid * DK_ + d] = expf(total);
}

// ---------------------------------------------------------------------------
// vtrans: qkv v-cols [bt][1024+ h*256 + dv] -> vT per-chunk [dv=256][j=64]
// ---------------------------------------------------------------------------
__global__ __launch_bounds__(256)
void vtrans_kernel(const ushort_t* __restrict__ qkv, ushort_t* __restrict__ vT) {
    __shared__ ushort_t vl[64][264];
    const int bid = blockIdx.x;
    const int c = bid & 31, bh = bid >> 5;
    const int b = bh >> 2, h = bh & 3;
    const int t0 = b * T_ + c * CC;
    const int t = threadIdx.x;

    #pragma unroll
    for (int m = 0; m < 8; ++m) {
        int p = t + m * 256;
        int j = p >> 5, d8 = (p & 31) * 8;
        *(uint4*)&vl[j][d8] =
            *(const uint4*)&qkv[(size_t)(t0 + j) * 2048 + 1024 + h * DV_ + d8];
    }
    __syncthreads();

    const size_t outb = (size_t)bid * (256 * 64);
    #pragma unroll
    for (int it = 0; it < 2; ++it) {
        int dv = it * 128 + (t >> 1);
        int j0 = (t & 1) * 32;
        u32 vv[16];
        #pragma unroll
        for (int wi = 0; wi < 16; ++wi)
            vv[wi] = (u32)vl[j0 + 2 * wi][dv] | ((u32)vl[j0 + 2 * wi + 1][dv] << 16);
        ushort_t* dst = &vT[outb + (size_t)dv * 64 + j0];
        *(uint4*)(dst + 0)  = make_uint4(vv[0], vv[1], vv[2], vv[3]);
        *(uint4*)(dst + 8)  = make_uint4(vv[4], vv[5], vv[6], vv[7]);
        *(uint4*)(dst + 16) = make_uint4(vv[8], vv[9], vv[10], vv[11]);
        *(uint4*)(dst + 24) = make_uint4(vv[12], vv[13], vv[14], vv[15]);
    }
}

// ---------------------------------------------------------------------------
// chunk_state (MFMA): Sst^T[dv=256][dk=128] = vT(256x64) @ kg(64x128)
// ---------------------------------------------------------------------------
__global__ __launch_bounds__(256)
void chunk_state(const ushort_t* __restrict__ kgb, const ushort_t* __restrict__ vT,
                 ushort_t* __restrict__ Sst) {
    __shared__ ushort_t kgT[128 * 72];
    const int bid = blockIdx.x;
    const int t = threadIdx.x;
    const size_t kgbase = (size_t)bid * (CC * DK_);
    const size_t vtbase = (size_t)bid * (256 * 64);
    const size_t sbase  = (size_t)bid * (256 * 128);

    #pragma unroll
    for (int m = 0; m < 4; ++m) {
        int p = t + m * 256;
        int j = p >> 4, d0 = (p & 15) * 8;
        uint4 r = *(const uint4*)&kgb[kgbase + (size_t)j * DK_ + d0];
        kgT[(d0 + 0) * 72 + j] = (ushort_t)(r.x & 0xffff);
        kgT[(d0 + 1) * 72 + j] = (ushort_t)(r.x >> 16);
        kgT[(d0 + 2) * 72 + j] = (ushort_t)(r.y & 0xffff);
        kgT[(d0 + 3) * 72 + j] = (ushort_t)(r.y >> 16);
        kgT[(d0 + 4) * 72 + j] = (ushort_t)(r.z & 0xffff);
        kgT[(d0 + 5) * 72 + j] = (ushort_t)(r.z >> 16);
        kgT[(d0 + 6) * 72 + j] = (ushort_t)(r.w & 0xffff);
        kgT[(d0 + 7) * 72 + j] = (ushort_t)(r.w >> 16);
    }
    __syncthreads();

    const int w = t >> 6, lane = t & 63;
    const int lm = lane & 15, lg = lane >> 4;
    #pragma unroll
    for (int mm = 0; mm < 4; ++mm) {
        const int mt = w * 4 + mm;
        short8 a0 = *(const short8*)&vT[vtbase + (size_t)(mt * 16 + lm) * 64 + lg * 8];
        short8 a1 = *(const short8*)&vT[vtbase + (size_t)(mt * 16 + lm) * 64 + 32 + lg * 8];
        #pragma unroll
        for (int n = 0; n < 8; ++n) {
            f32x4 acc = {0.f, 0.f, 0.f, 0.f};
            short8 b0 = *(const short8*)&kgT[(n * 16 + lm) * 72 + lg * 8];
            short8 b1 = *(const short8*)&kgT[(n * 16 + lm) * 72 + 32 + lg * 8];
            acc = __builtin_amdgcn_mfma_f32_16x16x32_bf16(a0, b0, acc, 0, 0, 0);
            acc = __builtin_amdgcn_mfma_f32_16x16x32_bf16(a1, b1, acc, 0, 0, 0);
            #pragma unroll
            for (int e = 0; e < 4; ++e)
                Sst[sbase + (size_t)(mt * 16 + lg * 4 + e) * 128 + n * 16 + lm] = f2b(acc[e]);
        }
    }
}

// ---------------------------------------------------------------------------
// scan_combine: in-place M_c -> exclusive prefix P_c. 256 blocks.
// ---------------------------------------------------------------------------
__global__ __launch_bounds__(256)
void scan_combine(ushort_t* __restrict__ Sst, const float* __restrict__ glast) {
    const int bid = blockIdx.x;
    const int dvt = bid & 15, bh = bid >> 4;
    const int t = threadIdx.x;
    const int dv = dvt * 16 + (t >> 4);
    const int dk0 = (t & 15) * 8;

    float P[8];
    #pragma unroll
    for (int e = 0; e < 8; ++e) P[e] = 0.f;

    for (int c = 0; c < NCH; ++c) {
        const size_t base = ((size_t)(bh * NCH + c) * 256 + dv) * 128 + dk0;
        uint4 m0 = *(const uint4*)&Sst[base];
        u32 wd[4];
        #pragma unroll
        for (int e = 0; e < 4; ++e)
            wd[e] = (u32)f2b(P[2 * e]) | ((u32)f2b(P[2 * e + 1]) << 16);
        *(uint4*)&Sst[base] = make_uint4(wd[0], wd[1], wd[2], wd[3]);
        float mv[8];
        unpack2(m0.x, mv[0], mv[1]); unpack2(m0.y, mv[2], mv[3]);
        unpack2(m0.z, mv[4], mv[5]); unpack2(m0.w, mv[6], mv[7]);
        const float* glp = &glast[(size_t)(bh * NCH + c) * DK_ + dk0];
        float4 g0 = *(const float4*)&glp[0];
        float4 g1 = *(const float4*)&glp[4];
        float gl[8] = {g0.x, g0.y, g0.z, g0.w, g1.x, g1.y, g1.z, g1.w};
        #pragma unroll
        for (int e = 0; e < 8; ++e) P[e] = gl[e] * P[e] + mv[e];
    }
}

// ---------------------------------------------------------------------------
// fused_chunk (MFMA): o = tril(qg@ki^T)@v + qg@P per chunk; bf16 out.
// ---------------------------------------------------------------------------
__global__ __launch_bounds__(256)
void fused_chunk(const ushort_t* __restrict__ qgb, const ushort_t* __restrict__ kib,
                 const ushort_t* __restrict__ vT, const ushort_t* __restrict__ Sst,
                 ushort_t* __restrict__ ob) {
    __shared__ __align__(16) ushort_t lds[24064];   // 48.1KB
    ushort_t* stg = lds;                 // [64][168]
    ushort_t* vq  = lds + 10752;         // [64][104]
    ushort_t* Al  = lds + 17408;         // [64][104]

    const int bid = blockIdx.x;
    const int c = bid & 31, bh = bid >> 5;
    const int b = bh >> 2, h = bh & 3;
    const int t0 = b * T_ + c * CC;
    const int t = threadIdx.x;
    const int w = t >> 6, lane = t & 63;
    const int lm = lane & 15, lg = lane >> 4;
    const int m0 = w * 16;

    const size_t qbase  = (size_t)bid * (CC * DK_);
    const size_t vtbase = (size_t)bid * (256 * 64);
    const size_t sbase  = (size_t)bid * (256 * 128);

    short8 qf[4];
    #pragma unroll
    for (int kk = 0; kk < 4; ++kk)
        qf[kk] = *(const short8*)&qgb[qbase + (size_t)(m0 + lm) * DK_ + kk * 32 + lg * 8];

    #pragma unroll
    for (int m = 0; m < 4; ++m) {
        int p = t + m * 256;
        int j = p >> 4, d0 = (p & 15) * 8;
        *(uint4*)&stg[j * 168 + d0] = *(const uint4*)&kib[qbase + (size_t)j * DK_ + d0];
    }
    __syncthreads();

    f32x4 accA[4];
    #pragma unroll
    for (int jt = 0; jt < 4; ++jt) accA[jt] = f32x4{0.f, 0.f, 0.f, 0.f};
    #pragma unroll
    for (int jt = 0; jt < 4; ++jt)
        #pragma unroll
        for (int kk = 0; kk < 4; ++kk) {
            short8 bfrag = *(const short8*)&stg[(jt * 16 + lm) * 168 + kk * 32 + lg * 8];
            accA[jt] = __builtin_amdgcn_mfma_f32_16x16x32_bf16(qf[kk], bfrag, accA[jt], 0, 0, 0);
        }
    #pragma unroll
    for (int jt = 0; jt < 4; ++jt)
        #pragma unroll
        for (int e = 0; e < 4; ++e) {
            int i = m0 + lg * 4 + e, j = jt * 16 + lm;
            Al[i * 104 + j] = f2b(j <= i ? accA[jt][e] : 0.f);
        }
    __syncthreads();

    short8 af[2];
    #pragma unroll
    for (int kk = 0; kk < 2; ++kk)
        af[kk] = *(const short8*)&Al[(m0 + lm) * 104 + kk * 32 + lg * 8];

    #pragma unroll 1
    for (int qq = 0; qq < 4; ++qq) {
        #pragma unroll
        for (int m = 0; m < 2; ++m) {
            int p = t + m * 256;
            int dvr = p >> 3, d0 = (p & 7) * 8;
            *(uint4*)&vq[dvr * 104 + d0] =
                *(const uint4*)&vT[vtbase + (size_t)(qq * 64 + dvr) * 64 + d0];
        }
        #pragma unroll
        for (int m = 0; m < 4; ++m) {
            int p = t + m * 256;
            int dvr = p >> 4, d0 = (p & 15) * 8;
            *(uint4*)&stg[dvr * 168 + d0] =
                *(const uint4*)&Sst[sbase + (size_t)(qq * 64 + dvr) * 128 + d0];
        }
        __syncthreads();
        #pragma unroll
        for (int n = 0; n < 4; ++n) {
            f32x4 acc = {0.f, 0.f, 0.f, 0.f};
            #pragma unroll
            for (int kk = 0; kk < 2; ++kk) {
                short8 bfrag = *(const short8*)&vq[(n * 16 + lm) * 104 + kk * 32 + lg * 8];
                acc = __builtin_amdgcn_mfma_f32_16x16x32_bf16(af[kk], bfrag, acc, 0, 0, 0);
            }
            #pragma unroll
            for (int kk = 0; kk < 4; ++kk) {
                short8 bfrag = *(const short8*)&stg[(n * 16 + lm) * 168 + kk * 32 + lg * 8];
                acc = __builtin_amdgcn_mfma_f32_16x16x32_bf16(qf[kk], bfrag, acc, 0, 0, 0);
            }
            #pragma unroll
            for (int e = 0; e < 4; ++e)
                ob[(size_t)(t0 + m0 + lg * 4 + e) * VD + h * DV_ + qq * 64 + n * 16 + lm] = f2b(acc[e]);
        }
        __syncthreads();
    }
}

// ---------------------------------------------------------------------------
// normgate: obf = bf16( RMSNorm(o)*gnw * swish(g) )
// ---------------------------------------------------------------------------
__global__ __launch_bounds__(256)
void normgate_kernel(const ushort_t* __restrict__ ob, const ushort_t* __restrict__ gbf,
                     const float* __restrict__ gnw, ushort_t* __restrict__ obf) {
    const int t = threadIdx.x;
    const int w = t >> 6, lane = t & 63;
    const int row = blockIdx.x * 4 + w;
    const size_t base = (size_t)row * DV_ + lane * 4;

    uint2 ov2 = *(const uint2*)&ob[base];
    float o0v, o1v, o2v, o3v;
    unpack2(ov2.x, o0v, o1v); unpack2(ov2.y, o2v, o3v);
    float ssq = o0v * o0v + o1v * o1v + o2v * o2v + o3v * o3v;
    #pragma unroll
    for (int off = 32; off > 0; off >>= 1) ssq += __shfl_xor(ssq, off);
    const float rms = rsqrtf(ssq * (1.0f / DV_) + 1e-5f);

    uint2 gv2 = *(const uint2*)&gbf[base];
    float g0, g1, g2, g3;
    unpack2(gv2.x, g0, g1); unpack2(gv2.y, g2, g3);
    float4 wv = *(const float4*)&gnw[lane * 4];
    float r0 = o0v * rms * wv.x * (g0 / (1.f + expf(-g0)));
    float r1 = o1v * rms * wv.y * (g1 / (1.f + expf(-g1)));
    float r2 = o2v * rms * wv.z * (g2 / (1.f + expf(-g2)));
    float r3 = o3v * rms * wv.w * (g3 / (1.f + expf(-g3)));
    uint2 p;
    p.x = (u32)f2b(r0) | ((u32)f2b(r1) << 16);
    p.y = (u32)f2b(r2) | ((u32)f2b(r3) << 16);
    *(uint2*)&obf[base] = p;
}

// ---------------------------------------------------------------------------
extern "C" void kernel_launch(void* const* d_in, const int* in_sizes, int n_in,
                              void* d_out, int out_size, void* d_ws, size_t ws_size,
                              hipStream_t stream) {
    const float* x    = (const float*)d_in[0];
    const float* Wq   = (const float*)d_in[1];
    const float* Wk   = (const float*)d_in[2];
    const float* Wv   = (const float*)d_in[3];
    const float* Wg   = (const float*)d_in[4];
    const float* Wgk1 = (const float*)d_in[5];
    const float* Wgk2 = (const float*)d_in[6];
    const float* bgk2 = (const float*)d_in[7];
    const float* Wo   = (const float*)d_in[8];
    const float* gnw  = (const float*)d_in[9];

    float* ws = (float*)d_ws;
    // ---- workspace (f32 word offsets; every size derived from sizeof) ----
    // qkv   [0,        8388608)  u16 BT*2048 = 16,777,216 u16 = 8,388,608 w
    //   late: ob  = qkv[0, 4194304)      (u16 BT*VD)
    //         gbf = qkv[4194304, 8388608) (u16 BT*VD)
    // vT    [8388608, 12582912)  u16 BT*VD = 4,194,304 w
    // Sst   [12582912,20971520)  u16 512*256*128 = 8,388,608 w
    //   early: wcat [12582912,13631488) u16 2048*1024 = 1,048,576 w
    //          wgt  [13631488,14155776) u16 1024*1024 =   524,288 w
    //   late:  obf  [12582912,16777216) u16 BT*VD
    //          wbfO [16777216,17301504) u16 1024*1024
    // xbf   [20971520,25165824)  u16 BT*DM = 4,194,304 w
    // qgb   [25165824,27262976)  u16 BT*KD = 2,097,152 w
    // kib   [27262976,29360128)
    // kgb   [29360128,31457280)
    // tmp16 [31457280,31588352)  f32 131,072 w
    // glast [31588352,31653888)  f32 65,536 w
    // w1t   [31653888,31662080)  u16 16,384 = 8,192 w
    // total 31,662,080 w = 126.6 MB
    ushort_t* qkv  = (ushort_t*)ws;
    ushort_t* ob   = (ushort_t*)ws;
    ushort_t* gbf  = (ushort_t*)(ws + 4194304);
    ushort_t* vT   = (ushort_t*)(ws + 8388608);
    ushort_t* Sst  = (ushort_t*)(ws + 12582912);
    ushort_t* wcat = (ushort_t*)(ws + 12582912);
    ushort_t* wgt  = (ushort_t*)(ws + 13631488);
    ushort_t* obf  = (ushort_t*)(ws + 12582912);
    ushort_t* wbfO = (ushort_t*)(ws + 16777216);
    ushort_t* xbf  = (ushort_t*)(ws + 20971520);
    ushort_t* qgb  = (ushort_t*)(ws + 25165824);
    ushort_t* kib  = (ushort_t*)(ws + 27262976);
    ushort_t* kgb  = (ushort_t*)(ws + 29360128);
    float* tmp16   = ws + 31457280;
    float* glast   = ws + 31588352;
    ushort_t* w1t  = (ushort_t*)(ws + 31653888);

    cvtx<<<4096, 256, 0, stream>>>(x, xbf, BT * DM);
    w1trans<<<64, 256, 0, stream>>>(Wgk1, w1t);

    // concatenated W^T: [q|k|v] rows (2048 x 1024); g weight separate
    tcvt<<<dim3(32, 16), 256, 0, stream>>>(Wq, wcat, DM, KD);
    tcvt<<<dim3(32, 16), 256, 0, stream>>>(Wk, wcat + (size_t)512 * 1024, DM, KD);
    tcvt<<<dim3(32, 32), 256, 0, stream>>>(Wv, wcat + (size_t)1024 * 1024, DM, VD);
    tcvt<<<dim3(32, 32), 256, 0, stream>>>(Wg, wgt, DM, VD);

    gemm_qkv<<<1024, 256, 0, stream>>>(xbf, wcat, qkv);

    lowrank_mfma<<<128, 256, 0, stream>>>(xbf, w1t, tmp16);
    gateprep_kernel<<<512, 128, 0, stream>>>(qkv, tmp16, Wgk2, bgk2, qgb, kib, kgb, glast);

    vtrans_kernel<<<512, 256, 0, stream>>>(qkv, vT);   // qkv fully dead after this

    gemm_bf16<1><<<512, 256, 0, stream>>>(xbf, wgt, gbf);   // g proj

    chunk_state<<<512, 256, 0, stream>>>(kgb, vT, Sst);
    scan_combine<<<256, 256, 0, stream>>>(Sst, glast);
    fused_chunk<<<512, 256, 0, stream>>>(qgb, kib, vT, Sst, ob);

    tcvt<<<dim3(32, 32), 256, 0, stream>>>(Wo, wbfO, VD, DM);   // after fused_chunk (Sst dead)
    normgate_kernel<<<8192, 256, 0, stream>>>(ob, gbf, gnw, obf);
    gemm_bf16<0><<<512, 256, 0, stream>>>(obf, wbfO, (float*)d_out);
}